// Round 8
// baseline (249.065 us; speedup 1.0000x reference)
//
#include <hip/hip_runtime.h>

// ---- problem constants ----
#define DM    1024
#define LSEQ  4096
#define BATCH 4
#define MROWS (BATCH * LSEQ)           // 16384 rows
#define MD    ((size_t)MROWS * DM)     // 16,777,216 elems
#define DD    ((size_t)DM * DM)        // 1,048,576 elems
#define CHUNK 32
#define NCH   (LSEQ / CHUNK)           // 128 chunks
#define NCHAIN (BATCH * DM)            // 4096 scan chains

typedef __attribute__((ext_vector_type(4))) float  f32x4;
typedef __attribute__((ext_vector_type(8))) __bf16 bf16x8;
typedef __attribute__((ext_vector_type(4))) __bf16 bf16x4;

__device__ __forceinline__ void gload_lds16(const void* g, void* l) {
  __builtin_amdgcn_global_load_lds(
      (const __attribute__((address_space(1))) void*)g,
      (__attribute__((address_space(3))) void*)l, 16, 0, 0);
}

// ---- fp32 -> bf16 converts ----
__global__ __launch_bounds__(256) void cvt_bf16(const float* __restrict__ in,
                                                __bf16* __restrict__ out) {
  size_t i = ((size_t)blockIdx.x * 256 + threadIdx.x) * 4;
  f32x4 f = *(const f32x4*)(in + i);
  bf16x4 o;
#pragma unroll
  for (int j = 0; j < 4; ++j) o[j] = (__bf16)f[j];
  *(bf16x4*)(out + i) = o;
}

__global__ __launch_bounds__(256) void cvt_w(const float* __restrict__ s0,
                                             const float* __restrict__ s1,
                                             const float* __restrict__ s2,
                                             const float* __restrict__ s3,
                                             __bf16* __restrict__ dst) {
  const float* sp = (blockIdx.z == 0) ? s0 : (blockIdx.z == 1) ? s1
                  : (blockIdx.z == 2) ? s2 : s3;
  size_t i = ((size_t)blockIdx.x * 256 + threadIdx.x) * 4;
  f32x4 f = *(const f32x4*)(sp + i);
  bf16x4 o;
#pragma unroll
  for (int j = 0; j < 4; ++j) o[j] = (__bf16)f[j];
  *(bf16x4*)(dst + (size_t)blockIdx.z * DD + i) = o;
}

// ===== 256x256 liveness-ordered read-ahead bf16 NT GEMM (BK=64) =====
// C[m][n] = sum_k A[m][k]*W[n][k].  8 waves (2Mx4N), 2x64KB LDS dbuf.
// Register sets a0,a1,b0,b1; clusters C00(a0b0) C01(a0b1) C10(a1b0) C11(a1b1).
// Each set is reloaded ONLY after its last consumer:
//   top:  stage kt+1; read b1,a1(kt);  [queue: a0 8|b0 4|b1 4|a1 8 = 24]
//   LGKM(12) C00; LGKM(8) C01; LGKM(0); vmcnt(0)+barrier
//   preload a0(kt+1); C10; preload b0(kt+1); C11
// Every ds group is issued >=2 MFMA clusters before its consuming wait, so
// the LDS pipe streams under the matrix pipe. SB_ fences pin group order
// (b1-before-a1 matters for LGKM(8)); rule-18 SB_ after every counted wait.
// ROUND-8 FIX: mid-loop b1 must read the B region (bufc + 32768) — round 7
// read the A tile (one-line regression introduced rewriting PRELOAD16_).

__device__ __forceinline__ int swz(int b) { return b ^ ((b >> 3) & 0x70); }

__device__ __forceinline__ bf16x8 ldf(const char* tile, int row, int k) {
  int lin = (row << 7) + (k << 1);
  return *(const bf16x8*)(tile + swz(lin));
}

// stage a full 256x64 operand tile (32KB): 4 issues x 512 thr x 16B.
// dest linear, source inverse-permuted through swz.  (verified in round 2)
__device__ __forceinline__ void stage_tile(const __bf16* __restrict__ base,
                                           char* tile, int k0, int t) {
#pragma unroll
  for (int is = 0; is < 4; ++is) {
    int d = is * 8192 + t * 16;
    int l = swz(d);
    int row = l >> 7, cb = l & 127;
    gload_lds16((const char*)base + (size_t)row * (DM * 2) + k0 * 2 + cb, tile + d);
  }
}

template <typename OutT>
__global__ __launch_bounds__(512, 1) void gemm_nt(const __bf16* __restrict__ A,
                                                  const __bf16* __restrict__ Wb,
                                                  OutT* __restrict__ Cb) {
  constexpr int K = DM, N = DM, NT = K / 64;
  __shared__ __attribute__((aligned(128))) char lds[131072];

  const __bf16* Wp = Wb + (size_t)blockIdx.z * DD;
  OutT* Cp = Cb + (size_t)blockIdx.z * MD;

  // bijective XCD swizzle: nwg = 4*64 = 256, divisible by 8
  const int orig = blockIdx.y * 4 + blockIdx.x;
  const int sid = (orig & 7) * 32 + (orig >> 3);
  const int bx = sid & 3, by = sid >> 2;
  const int m0 = by * 256, n0 = bx * 256;

  const int t = threadIdx.x, lane = t & 63, wv = t >> 6;
  const int wr = wv >> 2, wc = wv & 3;          // 2 x 4 waves, 128x64 each
  const int lrow = lane & 15, lk8 = (lane >> 4) * 8;

  const __bf16* Abase = A + (size_t)m0 * K;
  const __bf16* Bbase = Wp + (size_t)n0 * K;

  f32x4 acc[8][4] = {};
  bf16x8 a0[4][2], a1[4][2];     // A frags, halves mh=0/1
  bf16x8 b0[2][2], b1[2][2];     // B frags, halves nh=0/1

#define LDA_(dst, mh, tile)                                             \
  _Pragma("unroll") for (int mf = 0; mf < 4; ++mf)                      \
  _Pragma("unroll") for (int ks = 0; ks < 2; ++ks)                      \
    dst[mf][ks] = ldf(tile, wr * 128 + (mh) * 64 + mf * 16 + lrow, ks * 32 + lk8);
#define LDB_(dst, nh, tile)                                             \
  _Pragma("unroll") for (int nf = 0; nf < 2; ++nf)                      \
  _Pragma("unroll") for (int ks = 0; ks < 2; ++ks)                      \
    dst[nf][ks] = ldf(tile, wc * 64 + (nh) * 32 + nf * 16 + lrow, ks * 32 + lk8);
#define MFMA16_(av, bv, mh, nh)                                         \
  __builtin_amdgcn_s_setprio(1);                                        \
  _Pragma("unroll") for (int mf = 0; mf < 4; ++mf)                      \
  _Pragma("unroll") for (int nf = 0; nf < 2; ++nf)                      \
  _Pragma("unroll") for (int ks = 0; ks < 2; ++ks)                      \
    acc[(mh) * 4 + mf][(nh) * 2 + nf] = __builtin_amdgcn_mfma_f32_16x16x32_bf16( \
        av[mf][ks], bv[nf][ks], acc[(mh) * 4 + mf][(nh) * 2 + nf], 0, 0, 0); \
  __builtin_amdgcn_s_setprio(0);
#define SB_ __builtin_amdgcn_sched_barrier(0);
#define LGKM_(n)                                                        \
  asm volatile("s_waitcnt lgkmcnt(" #n ")" ::: "memory"); SB_

  // prologue: stage tile 0; preload b0,a0 of tile 0
  stage_tile(Abase, lds,         0, t);
  stage_tile(Bbase, lds + 32768, 0, t);
  asm volatile("s_waitcnt vmcnt(0)\n\ts_barrier" ::: "memory");
  SB_
  LDB_(b0, 0, lds + 32768); SB_
  LDA_(a0, 0, lds); SB_

#pragma unroll 1
  for (int kt = 0; kt < NT; ++kt) {
    char* bufc = lds + (kt & 1) * 65536;
    char* bufn = lds + ((kt & 1) ^ 1) * 65536;
    const bool s1 = (kt + 1 < NT);

    // top: stage next tile (vm); read this tile's b1 then a1 (ds)
    if (s1) {
      stage_tile(Abase, bufn,         (kt + 1) * 64, t);
      stage_tile(Bbase, bufn + 32768, (kt + 1) * 64, t);
    }
    SB_
    LDB_(b1, 1, bufc + 32768); SB_   // B region! (round-7 bug: read bufc)
    LDA_(a1, 1, bufc); SB_

    LGKM_(12)                        // a0,b0 resident (issued >=2 clusters ago)
    MFMA16_(a0, b0, 0, 0); SB_
    LGKM_(8)                         // b1 resident
    MFMA16_(a0, b1, 0, 1); SB_       // a0 dies
    LGKM_(0)                         // a1 resident; ALL bufc reads drained
    asm volatile("s_waitcnt vmcnt(0)\n\ts_barrier" ::: "memory");
    SB_

    // tail: preload next tile's a0/b0 only after their death points
    if (s1) { LDA_(a0, 0, bufn); SB_ }
    MFMA16_(a1, b0, 1, 0); SB_       // b0 dies
    if (s1) { LDB_(b0, 0, bufn + 32768); SB_ }
    MFMA16_(a1, b1, 1, 1); SB_       // a1,b1 die
  }
#undef LDA_
#undef LDB_
#undef MFMA16_
#undef LGKM_
#undef SB_

  // epilogue: C/D layout col=lane&15, row=(lane>>4)*4+j
#pragma unroll
  for (int mi = 0; mi < 8; ++mi) {
    int r0 = m0 + wr * 128 + (mi >> 2) * 64 + (mi & 3) * 16 + (lane >> 4) * 4;
#pragma unroll
    for (int ni = 0; ni < 4; ++ni) {
      int c0 = n0 + wc * 64 + (ni >> 1) * 32 + (ni & 1) * 16 + (lane & 15);
#pragma unroll
      for (int j = 0; j < 4; ++j) {
        float v = acc[mi][ni][j];
        if constexpr (__is_same(OutT, float))
          Cp[(size_t)(r0 + j) * N + c0] = v;
        else
          Cp[(size_t)(r0 + j) * N + c0] = (__bf16)v;
      }
    }
  }
}

// ---- chunk sums: csum[c][chain] = sum_t lam^(31-t) v_t over chunk c ----
__global__ __launch_bounds__(256) void scan_sum(const __bf16* __restrict__ v,
                                                float* __restrict__ csum,
                                                const float* __restrict__ decay) {
  int tid = blockIdx.x * 256 + threadIdx.x;
  int dg = tid & 255;
  int b  = (tid >> 8) & 3;
  int c  = tid >> 10;
  int d0 = dg * 4;
  float lam = decay[((d0 >> 6) << 1) + 1];
  f32x4 s = {0.f, 0.f, 0.f, 0.f};
  size_t base = ((size_t)b * LSEQ + (size_t)c * CHUNK) * DM + d0;
  for (int t = 0; t < CHUNK; ++t) {
    bf16x4 vv = *(const bf16x4*)(v + base);
    f32x4 vf = {(float)vv[0], (float)vv[1], (float)vv[2], (float)vv[3]};
    s = lam * s + vf;
    base += DM;
  }
  *(f32x4*)(csum + (size_t)c * NCHAIN + b * DM + d0) = s;
}

// ---- pass2: carry[c][chain] = full state entering chunk c ----
__global__ __launch_bounds__(256) void scan2(const float* __restrict__ csum,
                                             float* __restrict__ carry,
                                             const float* __restrict__ decay) {
  int i = blockIdx.x * 256 + threadIdx.x;
  int ch0 = i * 4;
  int d0 = ch0 & (DM - 1);
  float lam = decay[((d0 >> 6) << 1) + 1];
  float l2 = lam * lam, l4 = l2 * l2, l8 = l4 * l4, l16 = l8 * l8;
  float lamC = l16 * l16;
  f32x4 cs = {0.f, 0.f, 0.f, 0.f};
  for (int c = 0; c < NCH; ++c) {
    *(f32x4*)(carry + (size_t)c * NCHAIN + ch0) = cs;
    f32x4 sm = *(const f32x4*)(csum + (size_t)c * NCHAIN + ch0);
    cs = lamC * cs + sm;
  }
}

// ---- fused per-chunk: exact scan (carry-seeded) + y=q*s + LN + silu gate ----
__global__ __launch_bounds__(256) void fuse_chunk(
    const __bf16* __restrict__ qb, const __bf16* __restrict__ vb,
    const __bf16* __restrict__ gb, const float* __restrict__ carry,
    const float* __restrict__ decay, const float* __restrict__ ln_g,
    const float* __restrict__ ln_b, __bf16* __restrict__ y2) {
  const int blk = blockIdx.x;
  const int b = blk >> 7, c = blk & 127;
  const int t = threadIdx.x, lane = t & 63, wv = t >> 6;
  const int d0 = t * 4;
  const float lam = decay[((d0 >> 6) << 1) + 1];
  f32x4 s = *(const f32x4*)(carry + (size_t)c * NCHAIN + b * DM + d0);
  const size_t base0 = ((size_t)b * LSEQ + (size_t)c * CHUNK) * DM + d0;

  __shared__ float sbs[2][32][4];
  __shared__ float stats[32][2];

  f32x4 y[32];
#pragma unroll
  for (int r = 0; r < 32; ++r) {
    size_t base = base0 + (size_t)r * DM;
    bf16x4 v4 = *(const bf16x4*)(vb + base);
    bf16x4 q4 = *(const bf16x4*)(qb + base);
    f32x4 vf = {(float)v4[0], (float)v4[1], (float)v4[2], (float)v4[3]};
    s = lam * s + vf;
    f32x4 yy;
    float su = 0.f, sq = 0.f;
#pragma unroll
    for (int i = 0; i < 4; ++i) {
      float val = (float)q4[i] * s[i];
      yy[i] = val; su += val; sq += val * val;
    }
    y[r] = yy;
#pragma unroll
    for (int o = 32; o > 0; o >>= 1) {
      su += __shfl_xor(su, o);
      sq += __shfl_xor(sq, o);
    }
    if (lane == 0) { sbs[0][r][wv] = su; sbs[1][r][wv] = sq; }
  }
  __syncthreads();
  if (t < 32) {
    float su = sbs[0][t][0] + sbs[0][t][1] + sbs[0][t][2] + sbs[0][t][3];
    float sq = sbs[1][t][0] + sbs[1][t][1] + sbs[1][t][2] + sbs[1][t][3];
    float mu = su * (1.0f / DM);
    float var = sq * (1.0f / DM) - mu * mu;
    stats[t][0] = mu;
    stats[t][1] = rsqrtf(fmaxf(var, 0.0f) + 1e-5f);
  }
  __syncthreads();

  f32x4 lg = *(const f32x4*)(ln_g + d0);
  f32x4 lb = *(const f32x4*)(ln_b + d0);
#pragma unroll
  for (int r = 0; r < 32; ++r) {
    size_t base = base0 + (size_t)r * DM;
    bf16x4 g4 = *(const bf16x4*)(gb + base);
    const float mu = stats[r][0], rstd = stats[r][1];
    bf16x4 o4;
#pragma unroll
    for (int i = 0; i < 4; ++i) {
      float gv = (float)g4[i];
      float gate = gv / (1.0f + __expf(-gv));
      o4[i] = (__bf16)(fmaf((y[r][i] - mu) * rstd, lg[i], lb[i]) * gate);
    }
    *(bf16x4*)(y2 + base) = o4;
  }
}

extern "C" void kernel_launch(void* const* d_in, const int* in_sizes, int n_in,
                              void* d_out, int out_size, void* d_ws, size_t ws_size,
                              hipStream_t stream) {
  const float* x     = (const float*)d_in[0];
  const float* decay = (const float*)d_in[3];
  const float* Wq    = (const float*)d_in[4];
  const float* Wv    = (const float*)d_in[5];
  const float* Wo    = (const float*)d_in[6];
  const float* Wg    = (const float*)d_in[7];
  const float* lng   = (const float*)d_in[8];
  const float* lnb   = (const float*)d_in[9];
  float* out = (float*)d_out;

  char* ws = (char*)d_ws;
  size_t off = 0;
  auto alloc = [&](size_t bytes) -> void* {
    void* p = ws + off;
    off += (bytes + 255) & ~(size_t)255;
    return p;
  };
  __bf16* xb   = (__bf16*)alloc(MD * 2);        // x in bf16
  __bf16* w4   = (__bf16*)alloc(4 * DD * 2);    // Wq|Wv|Wg|Wo in bf16
  __bf16* qvg  = (__bf16*)alloc(3 * MD * 2);    // q|v|g
  __bf16* y2b  = (__bf16*)alloc(MD * 2);        // post-LN*gate in bf16
  float*  csum = (float*)alloc((size_t)NCH * NCHAIN * 4);
  float*  cry  = (float*)alloc((size_t)NCH * NCHAIN * 4);

  cvt_bf16<<<(int)(MD / 1024), 256, 0, stream>>>(x, xb);
  cvt_w<<<dim3((unsigned)(DD / 1024), 1, 4), 256, 0, stream>>>(Wq, Wv, Wg, Wo, w4);

  gemm_nt<__bf16><<<dim3(4, MROWS / 256, 3), 512, 0, stream>>>(xb, w4, qvg);

  scan_sum<<<(BATCH * NCH * (DM / 4)) / 256, 256, 0, stream>>>(qvg + MD, csum, decay);
  scan2<<<(NCHAIN / 4) / 256, 256, 0, stream>>>(csum, cry, decay);

  fuse_chunk<<<BATCH * NCH, 256, 0, stream>>>(qvg, qvg + MD, qvg + 2 * MD, cry,
                                              decay, lng, lnb, y2b);

  gemm_nt<float><<<dim3(4, MROWS / 256, 1), 512, 0, stream>>>(y2b, w4 + 3 * DD, out);
}

// Round 9
// 238.036 us; speedup vs baseline: 1.0463x; 1.0463x over previous
//
#include <hip/hip_runtime.h>

// ---- problem constants ----
#define DM    1024
#define LSEQ  4096
#define BATCH 4
#define MROWS (BATCH * LSEQ)           // 16384 rows
#define MD    ((size_t)MROWS * DM)     // 16,777,216 elems
#define DD    ((size_t)DM * DM)        // 1,048,576 elems
#define CHUNK 32
#define NCH   (LSEQ / CHUNK)           // 128 chunks
#define NCHAIN (BATCH * DM)            // 4096 scan chains

typedef __attribute__((ext_vector_type(4))) float  f32x4;
typedef __attribute__((ext_vector_type(8))) __bf16 bf16x8;
typedef __attribute__((ext_vector_type(4))) __bf16 bf16x4;

__device__ __forceinline__ void gload_lds16(const void* g, void* l) {
  __builtin_amdgcn_global_load_lds(
      (const __attribute__((address_space(1))) void*)g,
      (__attribute__((address_space(3))) void*)l, 16, 0, 0);
}

// ---- fp32 -> bf16 converts ----
__global__ __launch_bounds__(256) void cvt_bf16(const float* __restrict__ in,
                                                __bf16* __restrict__ out) {
  size_t i = ((size_t)blockIdx.x * 256 + threadIdx.x) * 4;
  f32x4 f = *(const f32x4*)(in + i);
  bf16x4 o;
#pragma unroll
  for (int j = 0; j < 4; ++j) o[j] = (__bf16)f[j];
  *(bf16x4*)(out + i) = o;
}

__global__ __launch_bounds__(256) void cvt_w(const float* __restrict__ s0,
                                             const float* __restrict__ s1,
                                             const float* __restrict__ s2,
                                             const float* __restrict__ s3,
                                             __bf16* __restrict__ dst) {
  const float* sp = (blockIdx.z == 0) ? s0 : (blockIdx.z == 1) ? s1
                  : (blockIdx.z == 2) ? s2 : s3;
  size_t i = ((size_t)blockIdx.x * 256 + threadIdx.x) * 4;
  f32x4 f = *(const f32x4*)(sp + i);
  bf16x4 o;
#pragma unroll
  for (int j = 0; j < 4; ++j) o[j] = (__bf16)f[j];
  *(bf16x4*)(dst + (size_t)blockIdx.z * DD + i) = o;
}

// ========= 128x128 dbuf bf16 NT GEMM, conflict-free swizzle, 4 blk/CU =======
// C[m][n] = sum_k A[m][k]*W[n][k].  BK=32, NT=32, 4 waves (2x2, 64x64 each).
// 32KB LDS (2 bufs x (A 8K + B 8K)), __launch_bounds__(256,4) -> 4 blocks/CU.
// Overlap mechanism = inter-block (m114): one block's stage/ds phase hides
// under other blocks' MFMAs. R5 retried WITH the 64B-row conflict fix:
//   fragment read = 16 consecutive rows at granule g=(lane>>4) -> bank cohort
//   (g, row&1) had 8 lanes = 8-way conflict (1.26e7 measured, 2.94x cost m136).
//   XOR swizzle b ^= ((b>>7)&3)<<4  => granule' = g ^ ((row>>1)&3): every
//   (granule, parity) cohort gets exactly 2 lanes = free (m136). Involution;
//   applied inverse on the gload_lds SOURCE, forward on ds_read (rule 21).

__device__ __forceinline__ int swz64(int b) { return b ^ (((b >> 7) & 3) << 4); }

__device__ __forceinline__ bf16x8 ldf64(const char* tile, int row, int k) {
  int lin = (row << 6) + (k << 1);
  return *(const bf16x8*)(tile + swz64(lin));
}

// stage one 128x32 tile (8KB): 2 issues x 256 thr x 16B, dest linear,
// source inverse-permuted through swz64.
__device__ __forceinline__ void stage_tile(const __bf16* __restrict__ base,
                                           char* tile, int k0, int t) {
#pragma unroll
  for (int is = 0; is < 2; ++is) {
    int d = is * 4096 + t * 16;
    int l = swz64(d);
    int row = l >> 6, cb = l & 63;
    gload_lds16((const char*)base + (size_t)row * (DM * 2) + k0 * 2 + cb, tile + d);
  }
}

template <typename OutT>
__global__ __launch_bounds__(256, 4) void gemm_nt(const __bf16* __restrict__ A,
                                                  const __bf16* __restrict__ Wb,
                                                  OutT* __restrict__ Cb) {
  constexpr int K = DM, N = DM, NT = K / 32;
  __shared__ __attribute__((aligned(128))) char lds[32768];
  // layout: [buf0: A 8K | B 8K][buf1: A 8K | B 8K]

  const __bf16* Wp = Wb + (size_t)blockIdx.z * DD;
  OutT* Cp = Cb + (size_t)blockIdx.z * MD;

  // bijective XCD swizzle within each z-slice: nwg_xy = 8*128 = 1024 (%8==0)
  const int orig = blockIdx.y * 8 + blockIdx.x;
  const int sid = (orig & 7) * 128 + (orig >> 3);
  const int bx = sid & 7, by = sid >> 3;
  const int m0 = by * 128, n0 = bx * 128;

  const int t = threadIdx.x, lane = t & 63, wv = t >> 6;
  const int wr = wv >> 1, wc = wv & 1;          // 2 x 2 waves, 64x64 each
  const int lrow = lane & 15, koff = (lane >> 4) * 8;

  const __bf16* Abase = A + (size_t)m0 * K;
  const __bf16* Bbase = Wp + (size_t)n0 * K;

  f32x4 acc[4][4] = {};
  bf16x8 a[4], b[4];

  // prologue: stage kt0 into buf0
  stage_tile(Abase, lds,        0, t);
  stage_tile(Bbase, lds + 8192, 0, t);
  asm volatile("s_waitcnt vmcnt(0)\n\ts_barrier" ::: "memory");

#pragma unroll 1
  for (int kt = 0; kt < NT; ++kt) {
    char* bufc = lds + (kt & 1) * 16384;
    char* bufn = lds + ((kt & 1) ^ 1) * 16384;
    if (kt + 1 < NT) {
      stage_tile(Abase, bufn,        (kt + 1) * 32, t);
      stage_tile(Bbase, bufn + 8192, (kt + 1) * 32, t);
    }
#pragma unroll
    for (int mf = 0; mf < 4; ++mf)
      a[mf] = ldf64(bufc, wr * 64 + mf * 16 + lrow, koff);
#pragma unroll
    for (int nf = 0; nf < 4; ++nf)
      b[nf] = ldf64(bufc + 8192, wc * 64 + nf * 16 + lrow, koff);
    __builtin_amdgcn_s_setprio(1);
#pragma unroll
    for (int mf = 0; mf < 4; ++mf)
#pragma unroll
      for (int nf = 0; nf < 4; ++nf)
        acc[mf][nf] = __builtin_amdgcn_mfma_f32_16x16x32_bf16(
            a[mf], b[nf], acc[mf][nf], 0, 0, 0);
    __builtin_amdgcn_s_setprio(0);
    // lgkm(0): our ds_reads of bufc done before next iter overwrites it;
    // vmcnt(0): stages into bufn arrived before next iter reads it.
    asm volatile("s_waitcnt vmcnt(0) lgkmcnt(0)\n\ts_barrier" ::: "memory");
  }

  // epilogue: C/D layout col=lane&15, row=(lane>>4)*4+j
#pragma unroll
  for (int mf = 0; mf < 4; ++mf) {
    int r0 = m0 + wr * 64 + mf * 16 + (lane >> 4) * 4;
#pragma unroll
    for (int nf = 0; nf < 4; ++nf) {
      int c0 = n0 + wc * 64 + nf * 16 + (lane & 15);
#pragma unroll
      for (int j = 0; j < 4; ++j) {
        float v = acc[mf][nf][j];
        if constexpr (__is_same(OutT, float))
          Cp[(size_t)(r0 + j) * N + c0] = v;
        else
          Cp[(size_t)(r0 + j) * N + c0] = (__bf16)v;
      }
    }
  }
}

// ---- chunk sums: csum[c][chain] = sum_t lam^(31-t) v_t over chunk c ----
__global__ __launch_bounds__(256) void scan_sum(const __bf16* __restrict__ v,
                                                float* __restrict__ csum,
                                                const float* __restrict__ decay) {
  int tid = blockIdx.x * 256 + threadIdx.x;
  int dg = tid & 255;
  int b  = (tid >> 8) & 3;
  int c  = tid >> 10;
  int d0 = dg * 4;
  float lam = decay[((d0 >> 6) << 1) + 1];
  f32x4 s = {0.f, 0.f, 0.f, 0.f};
  size_t base = ((size_t)b * LSEQ + (size_t)c * CHUNK) * DM + d0;
  for (int t = 0; t < CHUNK; ++t) {
    bf16x4 vv = *(const bf16x4*)(v + base);
    f32x4 vf = {(float)vv[0], (float)vv[1], (float)vv[2], (float)vv[3]};
    s = lam * s + vf;
    base += DM;
  }
  *(f32x4*)(csum + (size_t)c * NCHAIN + b * DM + d0) = s;
}

// ---- pass2: carry[c][chain] = full state entering chunk c ----
__global__ __launch_bounds__(256) void scan2(const float* __restrict__ csum,
                                             float* __restrict__ carry,
                                             const float* __restrict__ decay) {
  int i = blockIdx.x * 256 + threadIdx.x;
  int ch0 = i * 4;
  int d0 = ch0 & (DM - 1);
  float lam = decay[((d0 >> 6) << 1) + 1];
  float l2 = lam * lam, l4 = l2 * l2, l8 = l4 * l4, l16 = l8 * l8;
  float lamC = l16 * l16;
  f32x4 cs = {0.f, 0.f, 0.f, 0.f};
  for (int c = 0; c < NCH; ++c) {
    *(f32x4*)(carry + (size_t)c * NCHAIN + ch0) = cs;
    f32x4 sm = *(const f32x4*)(csum + (size_t)c * NCHAIN + ch0);
    cs = lamC * cs + sm;
  }
}

// ---- fused per-chunk: exact scan (carry-seeded) + y=q*s + LN + silu gate ----
__global__ __launch_bounds__(256) void fuse_chunk(
    const __bf16* __restrict__ qb, const __bf16* __restrict__ vb,
    const __bf16* __restrict__ gb, const float* __restrict__ carry,
    const float* __restrict__ decay, const float* __restrict__ ln_g,
    const float* __restrict__ ln_b, __bf16* __restrict__ y2) {
  const int blk = blockIdx.x;
  const int b = blk >> 7, c = blk & 127;
  const int t = threadIdx.x, lane = t & 63, wv = t >> 6;
  const int d0 = t * 4;
  const float lam = decay[((d0 >> 6) << 1) + 1];
  f32x4 s = *(const f32x4*)(carry + (size_t)c * NCHAIN + b * DM + d0);
  const size_t base0 = ((size_t)b * LSEQ + (size_t)c * CHUNK) * DM + d0;

  __shared__ float sbs[2][32][4];
  __shared__ float stats[32][2];

  f32x4 y[32];
#pragma unroll
  for (int r = 0; r < 32; ++r) {
    size_t base = base0 + (size_t)r * DM;
    bf16x4 v4 = *(const bf16x4*)(vb + base);
    bf16x4 q4 = *(const bf16x4*)(qb + base);
    f32x4 vf = {(float)v4[0], (float)v4[1], (float)v4[2], (float)v4[3]};
    s = lam * s + vf;
    f32x4 yy;
    float su = 0.f, sq = 0.f;
#pragma unroll
    for (int i = 0; i < 4; ++i) {
      float val = (float)q4[i] * s[i];
      yy[i] = val; su += val; sq += val * val;
    }
    y[r] = yy;
#pragma unroll
    for (int o = 32; o > 0; o >>= 1) {
      su += __shfl_xor(su, o);
      sq += __shfl_xor(sq, o);
    }
    if (lane == 0) { sbs[0][r][wv] = su; sbs[1][r][wv] = sq; }
  }
  __syncthreads();
  if (t < 32) {
    float su = sbs[0][t][0] + sbs[0][t][1] + sbs[0][t][2] + sbs[0][t][3];
    float sq = sbs[1][t][0] + sbs[1][t][1] + sbs[1][t][2] + sbs[1][t][3];
    float mu = su * (1.0f / DM);
    float var = sq * (1.0f / DM) - mu * mu;
    stats[t][0] = mu;
    stats[t][1] = rsqrtf(fmaxf(var, 0.0f) + 1e-5f);
  }
  __syncthreads();

  f32x4 lg = *(const f32x4*)(ln_g + d0);
  f32x4 lb = *(const f32x4*)(ln_b + d0);
#pragma unroll
  for (int r = 0; r < 32; ++r) {
    size_t base = base0 + (size_t)r * DM;
    bf16x4 g4 = *(const bf16x4*)(gb + base);
    const float mu = stats[r][0], rstd = stats[r][1];
    bf16x4 o4;
#pragma unroll
    for (int i = 0; i < 4; ++i) {
      float gv = (float)g4[i];
      float gate = gv / (1.0f + __expf(-gv));
      o4[i] = (__bf16)(fmaf((y[r][i] - mu) * rstd, lg[i], lb[i]) * gate);
    }
    *(bf16x4*)(y2 + base) = o4;
  }
}

extern "C" void kernel_launch(void* const* d_in, const int* in_sizes, int n_in,
                              void* d_out, int out_size, void* d_ws, size_t ws_size,
                              hipStream_t stream) {
  const float* x     = (const float*)d_in[0];
  const float* decay = (const float*)d_in[3];
  const float* Wq    = (const float*)d_in[4];
  const float* Wv    = (const float*)d_in[5];
  const float* Wo    = (const float*)d_in[6];
  const float* Wg    = (const float*)d_in[7];
  const float* lng   = (const float*)d_in[8];
  const float* lnb   = (const float*)d_in[9];
  float* out = (float*)d_out;

  char* ws = (char*)d_ws;
  size_t off = 0;
  auto alloc = [&](size_t bytes) -> void* {
    void* p = ws + off;
    off += (bytes + 255) & ~(size_t)255;
    return p;
  };
  __bf16* xb   = (__bf16*)alloc(MD * 2);        // x in bf16
  __bf16* w4   = (__bf16*)alloc(4 * DD * 2);    // Wq|Wv|Wg|Wo in bf16
  __bf16* qvg  = (__bf16*)alloc(3 * MD * 2);    // q|v|g
  __bf16* y2b  = (__bf16*)alloc(MD * 2);        // post-LN*gate in bf16
  float*  csum = (float*)alloc((size_t)NCH * NCHAIN * 4);
  float*  cry  = (float*)alloc((size_t)NCH * NCHAIN * 4);

  cvt_bf16<<<(int)(MD / 1024), 256, 0, stream>>>(x, xb);
  cvt_w<<<dim3((unsigned)(DD / 1024), 1, 4), 256, 0, stream>>>(Wq, Wv, Wg, Wo, w4);

  gemm_nt<__bf16><<<dim3(8, MROWS / 128, 3), 256, 0, stream>>>(xb, w4, qvg);

  scan_sum<<<(BATCH * NCH * (DM / 4)) / 256, 256, 0, stream>>>(qvg + MD, csum, decay);
  scan2<<<(NCHAIN / 4) / 256, 256, 0, stream>>>(csum, cry, decay);

  fuse_chunk<<<BATCH * NCH, 256, 0, stream>>>(qvg, qvg + MD, qvg + 2 * MD, cry,
                                              decay, lng, lnb, y2b);

  gemm_nt<float><<<dim3(8, MROWS / 128, 1), 256, 0, stream>>>(y2b, w4 + 3 * DD, out);
}

// Round 10
// 213.842 us; speedup vs baseline: 1.1647x; 1.1131x over previous
//
#include <hip/hip_runtime.h>

// ---- problem constants ----
#define DM    1024
#define LSEQ  4096
#define BATCH 4
#define MROWS (BATCH * LSEQ)           // 16384 rows
#define MD    ((size_t)MROWS * DM)     // 16,777,216 elems
#define DD    ((size_t)DM * DM)        // 1,048,576 elems
#define CHUNK 32
#define NCH   (LSEQ / CHUNK)           // 128 chunks
#define NCHAIN (BATCH * DM)            // 4096 scan chains

typedef __attribute__((ext_vector_type(4))) float  f32x4;
typedef __attribute__((ext_vector_type(8))) __bf16 bf16x8;
typedef __attribute__((ext_vector_type(4))) __bf16 bf16x4;

__device__ __forceinline__ void gload_lds16(const void* g, void* l) {
  __builtin_amdgcn_global_load_lds(
      (const __attribute__((address_space(1))) void*)g,
      (__attribute__((address_space(3))) void*)l, 16, 0, 0);
}

// ---- fp32 -> bf16 converts (8 elems/thread) ----
__global__ __launch_bounds__(256) void cvt_bf16(const float* __restrict__ in,
                                                __bf16* __restrict__ out) {
  size_t i = ((size_t)blockIdx.x * 256 + threadIdx.x) * 8;
  f32x4 f0 = *(const f32x4*)(in + i);
  f32x4 f1 = *(const f32x4*)(in + i + 4);
  bf16x8 o;
#pragma unroll
  for (int j = 0; j < 4; ++j) { o[j] = (__bf16)f0[j]; o[4 + j] = (__bf16)f1[j]; }
  *(bf16x8*)(out + i) = o;
}

__global__ __launch_bounds__(256) void cvt_w(const float* __restrict__ s0,
                                             const float* __restrict__ s1,
                                             const float* __restrict__ s2,
                                             const float* __restrict__ s3,
                                             __bf16* __restrict__ dst) {
  const float* sp = (blockIdx.z == 0) ? s0 : (blockIdx.z == 1) ? s1
                  : (blockIdx.z == 2) ? s2 : s3;
  size_t i = ((size_t)blockIdx.x * 256 + threadIdx.x) * 8;
  f32x4 f0 = *(const f32x4*)(sp + i);
  f32x4 f1 = *(const f32x4*)(sp + i + 4);
  bf16x8 o;
#pragma unroll
  for (int j = 0; j < 4; ++j) { o[j] = (__bf16)f0[j]; o[4 + j] = (__bf16)f1[j]; }
  *(bf16x8*)(dst + (size_t)blockIdx.z * DD + i) = o;
}

// ======================= 256x256 relaxed 4-phase bf16 NT GEMM ===============
// (R4 configuration — best measured: 115.0-115.8 us QVG, twice-validated.)
// C[m][n] = sum_k A[m][k] * W[n][k].  M=16384, N=K=1024.
// 8 waves (2Mx4N), BK=64, 128KiB LDS double-buffered.
// LDS halves aligned to phase readers (A: mh*128+wr*64+r64; B: nh*128+wc*32+r32).
// ONE barrier per phase (post-MFMA, fused with counted vmcnt in a single asm).
// Region safety: a phase's LDS readers complete before the phase-end barrier
// (MFMAs consumed them); stages into that region are only issued after it.

__device__ __forceinline__ int swz(int b) { return b ^ ((b >> 3) & 0x70); }

__device__ __forceinline__ bf16x8 ldf(const char* tile, int row, int k) {
  int lin = (row << 7) + (k << 1);
  return *(const bf16x8*)(tile + swz(lin));
}

__device__ __forceinline__ void stageA_half(const __bf16* Abase, char* tileA,
                                            int h, int k0, int t) {
#pragma unroll
  for (int is = 0; is < 2; ++is) {
    int d = h * 16384 + is * 8192 + t * 16;
    int l = swz(d);
    int lds_r = l >> 7, cb = l & 127;
    int g = ((lds_r >> 6) & 1) * 128 + h * 64 + (lds_r & 63);   // wr*128+h*64+r64
    gload_lds16((const char*)Abase + (size_t)g * (DM * 2) + k0 * 2 + cb, tileA + d);
  }
}
__device__ __forceinline__ void stageB_half(const __bf16* Bbase, char* tileB,
                                            int h, int k0, int t) {
#pragma unroll
  for (int is = 0; is < 2; ++is) {
    int d = h * 16384 + is * 8192 + t * 16;
    int l = swz(d);
    int lds_r = l >> 7, cb = l & 127;
    int g = ((lds_r >> 5) & 3) * 64 + h * 32 + (lds_r & 31);    // wc*64+h*32+r32
    gload_lds16((const char*)Bbase + (size_t)g * (DM * 2) + k0 * 2 + cb, tileB + d);
  }
}

template <typename OutT>
__global__ __launch_bounds__(512, 2) void gemm_nt(const __bf16* __restrict__ A,
                                                  const __bf16* __restrict__ Wb,
                                                  OutT* __restrict__ Cb) {
  constexpr int K = DM, N = DM, NT = K / 64;
  __shared__ __attribute__((aligned(128))) char lds[131072];

  const __bf16* Wp = Wb + (size_t)blockIdx.z * DD;
  OutT* Cp = Cb + (size_t)blockIdx.z * MD;

  // bijective XCD swizzle: nwg = 4*64 = 256, divisible by 8
  const int orig = blockIdx.y * 4 + blockIdx.x;
  const int sid = (orig & 7) * 32 + (orig >> 3);
  const int bx = sid & 3, by = sid >> 2;
  const int m0 = by * 256, n0 = bx * 256;

  const int t = threadIdx.x, lane = t & 63, wv = t >> 6;
  const int wr = wv >> 2, wc = wv & 3;          // 2 x 4 waves
  const int lrow = lane & 15, lk8 = (lane >> 4) * 8;

  const __bf16* Abase = A + (size_t)m0 * K;
  const __bf16* Bbase = Wp + (size_t)n0 * K;

  f32x4 acc[8][4] = {};
  bf16x8 a[4][2];        // current A mh-half frags
  bf16x8 bq[2][2][2];    // B frags [nh][nf][ks]

  char* buf0 = lds;             // A at +0, B at +32768 within each buf
  char* buf1 = lds + 65536;

  // prologue: kt0 halves {A0,B0,B1,A1} then kt1 same order (16 insts)
  stageA_half(Abase, buf0,         0, 0, t);
  stageB_half(Bbase, buf0 + 32768, 0, 0, t);
  stageB_half(Bbase, buf0 + 32768, 1, 0, t);
  stageA_half(Abase, buf0,         1, 0, t);
  stageA_half(Abase, buf1,         0, 64, t);
  stageB_half(Bbase, buf1 + 32768, 0, 64, t);
  stageB_half(Bbase, buf1 + 32768, 1, 64, t);
  stageA_half(Abase, buf1,         1, 64, t);
  asm volatile("s_waitcnt vmcnt(12)\n\ts_barrier" ::: "memory");

#define LDA_(mh)                                                        \
  _Pragma("unroll") for (int mf = 0; mf < 4; ++mf)                      \
  _Pragma("unroll") for (int ks = 0; ks < 2; ++ks)                      \
    a[mf][ks] = ldf(At, (mh) * 128 + wr * 64 + mf * 16 + lrow, ks * 32 + lk8);
#define LDB_(nh)                                                        \
  _Pragma("unroll") for (int nf = 0; nf < 2; ++nf)                      \
  _Pragma("unroll") for (int ks = 0; ks < 2; ++ks)                      \
    bq[nh][nf][ks] = ldf(Bt, (nh) * 128 + wc * 32 + nf * 16 + lrow, ks * 32 + lk8);
#define MFMA16_(mh, nh)                                                 \
  __builtin_amdgcn_s_setprio(1);                                        \
  _Pragma("unroll") for (int mf = 0; mf < 4; ++mf)                      \
  _Pragma("unroll") for (int nf = 0; nf < 2; ++nf)                      \
  _Pragma("unroll") for (int ks = 0; ks < 2; ++ks)                      \
    acc[(mh) * 4 + mf][(nh) * 2 + nf] = __builtin_amdgcn_mfma_f32_16x16x32_bf16( \
        a[mf][ks], bq[nh][nf][ks], acc[(mh) * 4 + mf][(nh) * 2 + nf], 0, 0, 0); \
  __builtin_amdgcn_s_setprio(0);
#define VMBAR_(n)                                                       \
  asm volatile("s_waitcnt vmcnt(" #n ")\n\ts_barrier" ::: "memory");
#define BAR_                                                            \
  asm volatile("s_barrier" ::: "memory");

#pragma unroll 1
  for (int kt = 0; kt < NT; ++kt) {
    char* bufc = lds + (kt & 1) * 65536;
    const char* At = bufc;
    const char* Bt = bufc + 32768;
    const int k2 = (kt + 2) << 6;
    const bool s2 = (kt + 2 < NT);

    // P1: ds A0+B0; MFMA(0,0); wait (kt)B1
    LDA_(0); LDB_(0);
    MFMA16_(0, 0);
    if (kt < NT - 1) { VMBAR_(10); } else { VMBAR_(2); }

    // P2: stage kt+2 {A0,B0} into dead regions; ds B1; MFMA(0,1); wait (kt)A1
    if (s2) {
      stageA_half(Abase, bufc,         0, k2, t);
      stageB_half(Bbase, bufc + 32768, 0, k2, t);
    }
    LDB_(1);
    MFMA16_(0, 1);
    if (s2) { VMBAR_(12); } else if (kt == NT - 2) { VMBAR_(8); } else { VMBAR_(0); }

    // P3: stage kt+2 B1; ds A1; MFMA(1,0); barrier
    if (s2) stageB_half(Bbase, bufc + 32768, 1, k2, t);
    LDA_(1);
    MFMA16_(1, 0);
    BAR_;

    // P4: stage kt+2 A1; regs-only MFMA; wait (kt+1){A0,B0}
    if (s2) stageA_half(Abase, bufc, 1, k2, t);
    MFMA16_(1, 1);
    if (s2) { VMBAR_(12); } else if (kt == NT - 2) { VMBAR_(4); } else { VMBAR_(0); }
  }
#undef LDA_
#undef LDB_
#undef MFMA16_
#undef VMBAR_
#undef BAR_

  // epilogue: C/D layout col=lane&15, row=(lane>>4)*4+j
#pragma unroll
  for (int mi = 0; mi < 8; ++mi) {
    int r0 = m0 + wr * 128 + (mi >> 2) * 64 + (mi & 3) * 16 + (lane >> 4) * 4;
#pragma unroll
    for (int ni = 0; ni < 4; ++ni) {
      int c0 = n0 + wc * 64 + (ni >> 1) * 32 + (ni & 1) * 16 + (lane & 15);
#pragma unroll
      for (int j = 0; j < 4; ++j) {
        float v = acc[mi][ni][j];
        if constexpr (__is_same(OutT, float))
          Cp[(size_t)(r0 + j) * N + c0] = v;
        else
          Cp[(size_t)(r0 + j) * N + c0] = (__bf16)v;
      }
    }
  }
}

// ---- chunk sums: csum[c][chain] = sum_t lam^(31-t) v_t over chunk c ----
__global__ __launch_bounds__(256) void scan_sum(const __bf16* __restrict__ v,
                                                float* __restrict__ csum,
                                                const float* __restrict__ decay) {
  int tid = blockIdx.x * 256 + threadIdx.x;
  int dg = tid & 255;
  int b  = (tid >> 8) & 3;
  int c  = tid >> 10;
  int d0 = dg * 4;
  float lam = decay[((d0 >> 6) << 1) + 1];
  f32x4 s = {0.f, 0.f, 0.f, 0.f};
  size_t base = ((size_t)b * LSEQ + (size_t)c * CHUNK) * DM + d0;
  for (int t = 0; t < CHUNK; ++t) {
    bf16x4 vv = *(const bf16x4*)(v + base);
    f32x4 vf = {(float)vv[0], (float)vv[1], (float)vv[2], (float)vv[3]};
    s = lam * s + vf;
    base += DM;
  }
  *(f32x4*)(csum + (size_t)c * NCHAIN + b * DM + d0) = s;
}

// ---- pass2: carry[c][chain] = full state entering chunk c ----
__global__ __launch_bounds__(256) void scan2(const float* __restrict__ csum,
                                             float* __restrict__ carry,
                                             const float* __restrict__ decay) {
  int i = blockIdx.x * 256 + threadIdx.x;
  int ch0 = i * 4;
  int d0 = ch0 & (DM - 1);
  float lam = decay[((d0 >> 6) << 1) + 1];
  float l2 = lam * lam, l4 = l2 * l2, l8 = l4 * l4, l16 = l8 * l8;
  float lamC = l16 * l16;
  f32x4 cs = {0.f, 0.f, 0.f, 0.f};
  for (int c = 0; c < NCH; ++c) {
    *(f32x4*)(carry + (size_t)c * NCHAIN + ch0) = cs;
    f32x4 sm = *(const f32x4*)(csum + (size_t)c * NCHAIN + ch0);
    cs = lamC * cs + sm;
  }
}

// ---- fused per-chunk: exact scan (carry-seeded) + y=q*s + LN + silu gate ----
__global__ __launch_bounds__(256) void fuse_chunk(
    const __bf16* __restrict__ qb, const __bf16* __restrict__ vb,
    const __bf16* __restrict__ gb, const float* __restrict__ carry,
    const float* __restrict__ decay, const float* __restrict__ ln_g,
    const float* __restrict__ ln_b, __bf16* __restrict__ y2) {
  const int blk = blockIdx.x;
  const int b = blk >> 7, c = blk & 127;
  const int t = threadIdx.x, lane = t & 63, wv = t >> 6;
  const int d0 = t * 4;
  const float lam = decay[((d0 >> 6) << 1) + 1];
  f32x4 s = *(const f32x4*)(carry + (size_t)c * NCHAIN + b * DM + d0);
  const size_t base0 = ((size_t)b * LSEQ + (size_t)c * CHUNK) * DM + d0;

  __shared__ float sbs[2][32][4];
  __shared__ float stats[32][2];

  f32x4 y[32];
#pragma unroll
  for (int r = 0; r < 32; ++r) {
    size_t base = base0 + (size_t)r * DM;
    bf16x4 v4 = *(const bf16x4*)(vb + base);
    bf16x4 q4 = *(const bf16x4*)(qb + base);
    f32x4 vf = {(float)v4[0], (float)v4[1], (float)v4[2], (float)v4[3]};
    s = lam * s + vf;
    f32x4 yy;
    float su = 0.f, sq = 0.f;
#pragma unroll
    for (int i = 0; i < 4; ++i) {
      float val = (float)q4[i] * s[i];
      yy[i] = val; su += val; sq += val * val;
    }
    y[r] = yy;
#pragma unroll
    for (int o = 32; o > 0; o >>= 1) {
      su += __shfl_xor(su, o);
      sq += __shfl_xor(sq, o);
    }
    if (lane == 0) { sbs[0][r][wv] = su; sbs[1][r][wv] = sq; }
  }
  __syncthreads();
  if (t < 32) {
    float su = sbs[0][t][0] + sbs[0][t][1] + sbs[0][t][2] + sbs[0][t][3];
    float sq = sbs[1][t][0] + sbs[1][t][1] + sbs[1][t][2] + sbs[1][t][3];
    float mu = su * (1.0f / DM);
    float var = sq * (1.0f / DM) - mu * mu;
    stats[t][0] = mu;
    stats[t][1] = rsqrtf(fmaxf(var, 0.0f) + 1e-5f);
  }
  __syncthreads();

  f32x4 lg = *(const f32x4*)(ln_g + d0);
  f32x4 lb = *(const f32x4*)(ln_b + d0);
#pragma unroll
  for (int r = 0; r < 32; ++r) {
    size_t base = base0 + (size_t)r * DM;
    bf16x4 g4 = *(const bf16x4*)(gb + base);
    const float mu = stats[r][0], rstd = stats[r][1];
    bf16x4 o4;
#pragma unroll
    for (int i = 0; i < 4; ++i) {
      float gv = (float)g4[i];
      float gate = gv / (1.0f + __expf(-gv));
      o4[i] = (__bf16)(fmaf((y[r][i] - mu) * rstd, lg[i], lb[i]) * gate);
    }
    *(bf16x4*)(y2 + base) = o4;
  }
}

extern "C" void kernel_launch(void* const* d_in, const int* in_sizes, int n_in,
                              void* d_out, int out_size, void* d_ws, size_t ws_size,
                              hipStream_t stream) {
  const float* x     = (const float*)d_in[0];
  const float* decay = (const float*)d_in[3];
  const float* Wq    = (const float*)d_in[4];
  const float* Wv    = (const float*)d_in[5];
  const float* Wo    = (const float*)d_in[6];
  const float* Wg    = (const float*)d_in[7];
  const float* lng   = (const float*)d_in[8];
  const float* lnb   = (const float*)d_in[9];
  float* out = (float*)d_out;

  char* ws = (char*)d_ws;
  size_t off = 0;
  auto alloc = [&](size_t bytes) -> void* {
    void* p = ws + off;
    off += (bytes + 255) & ~(size_t)255;
    return p;
  };
  __bf16* xb   = (__bf16*)alloc(MD * 2);        // x in bf16
  __bf16* w4   = (__bf16*)alloc(4 * DD * 2);    // Wq|Wv|Wg|Wo in bf16
  __bf16* qvg  = (__bf16*)alloc(3 * MD * 2);    // q|v|g
  __bf16* y2b  = (__bf16*)alloc(MD * 2);        // post-LN*gate in bf16
  float*  csum = (float*)alloc((size_t)NCH * NCHAIN * 4);
  float*  cry  = (float*)alloc((size_t)NCH * NCHAIN * 4);

  cvt_bf16<<<(int)(MD / 2048), 256, 0, stream>>>(x, xb);
  cvt_w<<<dim3((unsigned)(DD / 2048), 1, 4), 256, 0, stream>>>(Wq, Wv, Wg, Wo, w4);

  gemm_nt<__bf16><<<dim3(4, MROWS / 256, 3), 512, 0, stream>>>(xb, w4, qvg);

  scan_sum<<<(BATCH * NCH * (DM / 4)) / 256, 256, 0, stream>>>(qvg + MD, csum, decay);
  scan2<<<(NCHAIN / 4) / 256, 256, 0, stream>>>(csum, cry, decay);

  fuse_chunk<<<BATCH * NCH, 256, 0, stream>>>(qvg, qvg + MD, qvg + 2 * MD, cry,
                                              decay, lng, lnb, y2b);

  gemm_nt<float><<<dim3(4, MROWS / 256, 1), 512, 0, stream>>>(y2b, w4 + 3 * DD, out);
}